// Round 1
// baseline (931.094 us; speedup 1.0000x reference)
//
#include <hip/hip_runtime.h>

#define D 128

// GEMM + bias + relu: h[i][j] = relu(sum_k x[i][k]*W[k][j] + b[j])
// W (64 KiB) staged in LDS once per block; grid-stride over row pairs.
__global__ __launch_bounds__(256) void gemm_relu_kernel(
    const float* __restrict__ x, const float* __restrict__ W,
    const float* __restrict__ bias, float* __restrict__ h, int N)
{
    __shared__ float Ws[D * D];
    __shared__ float bs[D];
    __shared__ float xs[2][D];

    // stage W into LDS, float4 coalesced (4096 float4 / 256 threads = 16 iters)
    const float4* W4 = (const float4*)W;
    float4* Ws4 = (float4*)Ws;
    for (int t = threadIdx.x; t < D * D / 4; t += 256) Ws4[t] = W4[t];
    if (threadIdx.x < D) bs[threadIdx.x] = bias[threadIdx.x];
    __syncthreads();

    const int j   = threadIdx.x & (D - 1);  // output column
    const int sub = threadIdx.x >> 7;       // which row of the pair (0/1)

    for (int row0 = (int)blockIdx.x * 2; row0 < N; row0 += (int)gridDim.x * 2) {
        const int row = row0 + sub;
        if (row < N) xs[sub][j] = x[(size_t)row * D + j];
        __syncthreads();
        if (row < N) {
            float acc = bs[j];
            const float4* xv4 = (const float4*)xs[sub];
            #pragma unroll
            for (int k4 = 0; k4 < D / 4; ++k4) {
                float4 xv = xv4[k4];   // ds_read_b128, wave-uniform broadcast
                int kb = k4 * 4;
                // Ws[k*128+j]: lanes j, j+32 hit same bank (2-way) => free
                acc = fmaf(xv.x, Ws[(kb + 0) * D + j], acc);
                acc = fmaf(xv.y, Ws[(kb + 1) * D + j], acc);
                acc = fmaf(xv.z, Ws[(kb + 2) * D + j], acc);
                acc = fmaf(xv.w, Ws[(kb + 3) * D + j], acc);
            }
            h[(size_t)row * D + j] = fmaxf(acc, 0.0f);
        }
        __syncthreads();  // xs reused next iteration
    }
}

// Edge scatter-max: 32 lanes per edge, float4 per lane.
// relu output >= 0, so uint atomicMax on the IEEE bit pattern is order-correct,
// and out pre-zeroed handles both empty segments and the max(.,0) clamp.
__global__ __launch_bounds__(256) void scatter_max_kernel(
    const int* __restrict__ rows, const int* __restrict__ cols,
    const float* __restrict__ h, unsigned int* __restrict__ out, int E)
{
    int gid = (int)blockIdx.x * 256 + (int)threadIdx.x;
    int e = gid >> 5;
    if (e >= E) return;
    int t = gid & 31;
    int r = rows[e];
    int c = cols[e];
    float4 v = ((const float4*)(h + (size_t)c * D))[t];
    unsigned int* o = out + (size_t)r * D + t * 4;
    // skip exact zeros: out is already 0 — halves atomic traffic (relu kills ~50%)
    if (v.x > 0.0f) atomicMax(o + 0, __float_as_uint(v.x));
    if (v.y > 0.0f) atomicMax(o + 1, __float_as_uint(v.y));
    if (v.z > 0.0f) atomicMax(o + 2, __float_as_uint(v.z));
    if (v.w > 0.0f) atomicMax(o + 3, __float_as_uint(v.w));
}

extern "C" void kernel_launch(void* const* d_in, const int* in_sizes, int n_in,
                              void* d_out, int out_size, void* d_ws, size_t ws_size,
                              hipStream_t stream) {
    const float* x    = (const float*)d_in[0];
    const int*   ei   = (const int*)d_in[1];   // [2, E] int32 (harness int convention)
    const float* W    = (const float*)d_in[2];
    const float* bias = (const float*)d_in[3];

    const int N = in_sizes[0] / D;   // 40000
    const int E = in_sizes[1] / 2;   // 640000
    const int* rows = ei;        // edge_index[0]
    const int* cols = ei + E;    // edge_index[1]

    float* h = (float*)d_ws;     // [N, D] fp32 = 20.48 MB scratch

    // zero output: implements empty-segment fill AND max(agg, 0) clamp
    hipMemsetAsync(d_out, 0, (size_t)out_size * sizeof(float), stream);

    gemm_relu_kernel<<<512, 256, 0, stream>>>(x, W, bias, h, N);

    long long nthreads = (long long)E * 32;
    int nblocks = (int)((nthreads + 255) / 256);
    scatter_max_kernel<<<nblocks, 256, 0, stream>>>(rows, cols, h,
                                                    (unsigned int*)d_out, E);
}

// Round 2
// 342.110 us; speedup vs baseline: 2.7216x; 2.7216x over previous
//
#include <hip/hip_runtime.h>

#define D 128

// GEMM + bias + relu: h[i][j] = relu(sum_k x[i][k]*W[k][j] + b[j])
// W (64 KiB) staged in LDS once per block; grid-stride over row pairs.
__global__ __launch_bounds__(256) void gemm_relu_kernel(
    const float* __restrict__ x, const float* __restrict__ W,
    const float* __restrict__ bias, float* __restrict__ h, int N)
{
    __shared__ float Ws[D * D];
    __shared__ float bs[D];
    __shared__ float xs[2][D];

    const float4* W4 = (const float4*)W;
    float4* Ws4 = (float4*)Ws;
    for (int t = threadIdx.x; t < D * D / 4; t += 256) Ws4[t] = W4[t];
    if (threadIdx.x < D) bs[threadIdx.x] = bias[threadIdx.x];
    __syncthreads();

    const int j   = threadIdx.x & (D - 1);
    const int sub = threadIdx.x >> 7;

    for (int row0 = (int)blockIdx.x * 2; row0 < N; row0 += (int)gridDim.x * 2) {
        const int row = row0 + sub;
        if (row < N) xs[sub][j] = x[(size_t)row * D + j];
        __syncthreads();
        if (row < N) {
            float acc = bs[j];
            const float4* xv4 = (const float4*)xs[sub];
            #pragma unroll
            for (int k4 = 0; k4 < D / 4; ++k4) {
                float4 xv = xv4[k4];
                int kb = k4 * 4;
                acc = fmaf(xv.x, Ws[(kb + 0) * D + j], acc);
                acc = fmaf(xv.y, Ws[(kb + 1) * D + j], acc);
                acc = fmaf(xv.z, Ws[(kb + 2) * D + j], acc);
                acc = fmaf(xv.w, Ws[(kb + 3) * D + j], acc);
            }
            h[(size_t)row * D + j] = fmaxf(acc, 0.0f);
        }
        __syncthreads();
    }
}

// ---------- CSR build ----------
__global__ __launch_bounds__(256) void hist_kernel(
    const int* __restrict__ rows, int* __restrict__ deg, int E)
{
    int e = (int)blockIdx.x * 256 + (int)threadIdx.x;
    if (e < E) atomicAdd(&deg[rows[e]], 1);
}

// Single-block exclusive scan over deg[N] -> edge_ptr[N+1]; also seeds cursor.
__global__ __launch_bounds__(256) void scan_kernel(
    const int* __restrict__ deg, int* __restrict__ edge_ptr,
    int* __restrict__ cursor, int N)
{
    __shared__ int partial[256];
    const int tid = threadIdx.x;
    const int chunk = (N + 255) / 256;
    const int start = tid * chunk;
    const int end   = min(start + chunk, N);

    int sum = 0;
    for (int i = start; i < end; ++i) sum += deg[i];
    partial[tid] = sum;
    __syncthreads();
    // Hillis-Steele inclusive scan over 256 partials
    for (int off = 1; off < 256; off <<= 1) {
        int v = (tid >= off) ? partial[tid - off] : 0;
        __syncthreads();
        partial[tid] += v;
        __syncthreads();
    }
    int base = (tid == 0) ? 0 : partial[tid - 1];
    for (int i = start; i < end; ++i) {
        edge_ptr[i] = base;
        cursor[i]   = base;
        base += deg[i];
    }
    if (tid == 0) edge_ptr[N] = partial[255];
}

__global__ __launch_bounds__(256) void scatter_kernel(
    const int* __restrict__ rows, const int* __restrict__ cols,
    int* __restrict__ cursor, int* __restrict__ cols_sorted, int E)
{
    int e = (int)blockIdx.x * 256 + (int)threadIdx.x;
    if (e < E) {
        int r = rows[e];
        int pos = atomicAdd(&cursor[r], 1);
        cols_sorted[pos] = cols[e];
    }
}

// One wave (64 lanes) per node, float2 per lane: register max, zero atomics.
// acc starts at 0 => empty segments and the max(.,0) clamp both handled.
__global__ __launch_bounds__(256) void aggregate_kernel(
    const int* __restrict__ edge_ptr, const int* __restrict__ cols_sorted,
    const float* __restrict__ h, float* __restrict__ out, int N)
{
    int node = (int)blockIdx.x * 4 + ((int)threadIdx.x >> 6);
    if (node >= N) return;
    int lane = threadIdx.x & 63;
    int beg = edge_ptr[node];
    int end = edge_ptr[node + 1];
    const float2* h2 = (const float2*)h;
    float2 acc = make_float2(0.0f, 0.0f);
    int i = beg;
    for (; i + 1 < end; i += 2) {           // 2-deep to keep gathers in flight
        int c0 = cols_sorted[i];
        int c1 = cols_sorted[i + 1];
        float2 v0 = h2[(size_t)c0 * 64 + lane];
        float2 v1 = h2[(size_t)c1 * 64 + lane];
        acc.x = fmaxf(fmaxf(acc.x, v0.x), v1.x);
        acc.y = fmaxf(fmaxf(acc.y, v0.y), v1.y);
    }
    if (i < end) {
        int c = cols_sorted[i];
        float2 v = h2[(size_t)c * 64 + lane];
        acc.x = fmaxf(acc.x, v.x);
        acc.y = fmaxf(acc.y, v.y);
    }
    ((float2*)out)[(size_t)node * 64 + lane] = acc;
}

// ---------- R0 fallback (atomic scatter-max) if d_ws is too small ----------
__global__ __launch_bounds__(256) void scatter_max_kernel(
    const int* __restrict__ rows, const int* __restrict__ cols,
    const float* __restrict__ h, unsigned int* __restrict__ out, int E)
{
    int gid = (int)blockIdx.x * 256 + (int)threadIdx.x;
    int e = gid >> 5;
    if (e >= E) return;
    int t = gid & 31;
    int r = rows[e];
    int c = cols[e];
    float4 v = ((const float4*)(h + (size_t)c * D))[t];
    unsigned int* o = out + (size_t)r * D + t * 4;
    if (v.x > 0.0f) atomicMax(o + 0, __float_as_uint(v.x));
    if (v.y > 0.0f) atomicMax(o + 1, __float_as_uint(v.y));
    if (v.z > 0.0f) atomicMax(o + 2, __float_as_uint(v.z));
    if (v.w > 0.0f) atomicMax(o + 3, __float_as_uint(v.w));
}

extern "C" void kernel_launch(void* const* d_in, const int* in_sizes, int n_in,
                              void* d_out, int out_size, void* d_ws, size_t ws_size,
                              hipStream_t stream) {
    const float* x    = (const float*)d_in[0];
    const int*   ei   = (const int*)d_in[1];
    const float* W    = (const float*)d_in[2];
    const float* bias = (const float*)d_in[3];

    const int N = in_sizes[0] / D;   // 40000
    const int E = in_sizes[1] / 2;   // 640000
    const int* rows = ei;
    const int* cols = ei + E;

    // d_ws layout
    char* ws = (char*)d_ws;
    size_t off_h    = 0;
    size_t off_deg  = off_h + (size_t)N * D * sizeof(float);
    size_t off_cur  = off_deg + (size_t)N * sizeof(int);
    size_t off_ptr  = off_cur + (size_t)N * sizeof(int);
    size_t off_cs   = off_ptr + (((size_t)(N + 1) * sizeof(int) + 15) & ~(size_t)15);
    size_t need     = off_cs + (size_t)E * sizeof(int);

    float* h = (float*)(ws + off_h);

    gemm_relu_kernel<<<512, 256, 0, stream>>>(x, W, bias, h, N);

    if (ws_size >= need) {
        int* deg         = (int*)(ws + off_deg);
        int* cursor      = (int*)(ws + off_cur);
        int* edge_ptr    = (int*)(ws + off_ptr);
        int* cols_sorted = (int*)(ws + off_cs);

        hipMemsetAsync(deg, 0, (size_t)N * sizeof(int), stream);
        hist_kernel<<<(E + 255) / 256, 256, 0, stream>>>(rows, deg, E);
        scan_kernel<<<1, 256, 0, stream>>>(deg, edge_ptr, cursor, N);
        scatter_kernel<<<(E + 255) / 256, 256, 0, stream>>>(rows, cols, cursor,
                                                            cols_sorted, E);
        aggregate_kernel<<<(N + 3) / 4, 256, 0, stream>>>(edge_ptr, cols_sorted,
                                                          h, (float*)d_out, N);
    } else {
        // fallback: R0 atomic path
        hipMemsetAsync(d_out, 0, (size_t)out_size * sizeof(float), stream);
        long long nthreads = (long long)E * 32;
        int nblocks = (int)((nthreads + 255) / 256);
        scatter_max_kernel<<<nblocks, 256, 0, stream>>>(rows, cols, h,
                                                        (unsigned int*)d_out, E);
    }
}

// Round 3
// 198.817 us; speedup vs baseline: 4.6832x; 1.7207x over previous
//
#include <hip/hip_runtime.h>

#define D 128
#define PADK 136   // LDS row stride (elems): +8 bf16 => rows shift 4 banks, 2-way max (free)

typedef __attribute__((ext_vector_type(8))) short short8;
typedef __attribute__((ext_vector_type(4))) float floatx4;

// fp32 -> bf16 (RNE) raw bits, no header dependence
static __device__ __forceinline__ unsigned short f2b(float f) {
    union { float f; unsigned int u; } v; v.f = f;
    return (unsigned short)((v.u + 0x7FFFu + ((v.u >> 16) & 1u)) >> 16);
}

// ---------------- GEMM + bias + relu via MFMA 16x16x32 bf16 ----------------
// Block = 256 threads (4 waves), 64 rows/block. W transposed+converted into
// LDS as Wt[n][k]; x tile converted into Xs[r][k]. Each wave: 16 rows x 128 cols.
__global__ __launch_bounds__(256) void gemm_mfma_kernel(
    const float* __restrict__ x, const float* __restrict__ W,
    const float* __restrict__ bias, unsigned short* __restrict__ h, int M)
{
    __shared__ unsigned short Wt[D * PADK];   // 34816 B
    __shared__ unsigned short Xs[64 * PADK];  // 17408 B

    const int tid = threadIdx.x;

    // stage W (fp32 [k][n]) -> Wt bf16 [n][k]
    for (int idx = tid * 4; idx < D * D; idx += 1024) {
        float4 w4 = *(const float4*)(W + idx);
        int k = idx >> 7, n = idx & (D - 1);
        Wt[(n + 0) * PADK + k] = f2b(w4.x);
        Wt[(n + 1) * PADK + k] = f2b(w4.y);
        Wt[(n + 2) * PADK + k] = f2b(w4.z);
        Wt[(n + 3) * PADK + k] = f2b(w4.w);
    }
    // stage x tile (fp32) -> Xs bf16 [r][k]
    const int r0 = (int)blockIdx.x * 64;
    for (int idx = tid * 4; idx < 64 * D; idx += 1024) {
        int r = idx >> 7, k = idx & (D - 1);
        if (r0 + r < M) {
            float4 x4 = *(const float4*)(x + (size_t)(r0 + r) * D + k);
            Xs[r * PADK + k + 0] = f2b(x4.x);
            Xs[r * PADK + k + 1] = f2b(x4.y);
            Xs[r * PADK + k + 2] = f2b(x4.z);
            Xs[r * PADK + k + 3] = f2b(x4.w);
        }
    }
    __syncthreads();

    const int wave = tid >> 6, lane = tid & 63;
    const int rw = wave * 16;              // wave's row base within tile
    const int mrow = lane & 15, quad = lane >> 4;

    // A frags: lane holds A[m=lane&15][k = kc*32 + quad*8 + j]  (m89-verified)
    short8 a[4];
    #pragma unroll
    for (int kc = 0; kc < 4; ++kc)
        a[kc] = *(const short8*)(&Xs[(rw + mrow) * PADK + kc * 32 + quad * 8]);

    #pragma unroll
    for (int t = 0; t < 8; ++t) {          // 8 col-tiles of 16
        const int n0 = t * 16;
        floatx4 acc = {0.f, 0.f, 0.f, 0.f};
        #pragma unroll
        for (int kc = 0; kc < 4; ++kc) {
            // B frag: lane holds B[k = kc*32 + quad*8 + j][n = lane&15]
            short8 b = *(const short8*)(&Wt[(n0 + mrow) * PADK + kc * 32 + quad * 8]);
            acc = __builtin_amdgcn_mfma_f32_16x16x32_bf16(a[kc], b, acc, 0, 0, 0);
        }
        const int col = n0 + mrow;
        const float bv = bias[col];
        #pragma unroll
        for (int r = 0; r < 4; ++r) {      // C/D: col=lane&15, row=quad*4+reg
            int row = r0 + rw + quad * 4 + r;
            if (row < M)
                h[(size_t)row * D + col] = f2b(fmaxf(acc[r] + bv, 0.0f));
        }
    }
}

// ---------------- CSR build ----------------
__global__ __launch_bounds__(256) void hist_kernel(
    const int* __restrict__ rows, int* __restrict__ deg, int E)
{
    int e = (int)blockIdx.x * 256 + (int)threadIdx.x;
    if (e < E) atomicAdd(&deg[rows[e]], 1);
}

// phase 1: per-block (1024 elems) local exclusive scan + block sums
__global__ __launch_bounds__(256) void scan1_kernel(
    const int* __restrict__ deg, int* __restrict__ edge_ptr,
    int* __restrict__ bsum, int N)
{
    __shared__ int part[256];
    const int tid = threadIdx.x;
    const int g0 = (int)blockIdx.x * 1024 + tid * 4;
    int d0 = 0, d1 = 0, d2 = 0, d3 = 0;
    if (g0 + 3 < N) {
        int4 d = *(const int4*)(deg + g0);
        d0 = d.x; d1 = d.y; d2 = d.z; d3 = d.w;
    } else {
        if (g0 + 0 < N) d0 = deg[g0 + 0];
        if (g0 + 1 < N) d1 = deg[g0 + 1];
        if (g0 + 2 < N) d2 = deg[g0 + 2];
        if (g0 + 3 < N) d3 = deg[g0 + 3];
    }
    const int s = d0 + d1 + d2 + d3;
    part[tid] = s;
    __syncthreads();
    for (int off = 1; off < 256; off <<= 1) {
        int v = (tid >= off) ? part[tid - off] : 0;
        __syncthreads();
        part[tid] += v;
        __syncthreads();
    }
    int ex = part[tid] - s;
    if (tid == 255) bsum[blockIdx.x] = part[255];
    if (g0 + 0 < N) edge_ptr[g0 + 0] = ex; ex += d0;
    if (g0 + 1 < N) edge_ptr[g0 + 1] = ex; ex += d1;
    if (g0 + 2 < N) edge_ptr[g0 + 2] = ex; ex += d2;
    if (g0 + 3 < N) edge_ptr[g0 + 3] = ex;
}

// phase 2: one wave scans the (<=64) block sums in-place to exclusive
__global__ __launch_bounds__(64) void scan2_kernel(int* bsum, int nb)
{
    const int tid = threadIdx.x;
    int v = (tid < nb) ? bsum[tid] : 0;
    const int orig = v;
    for (int off = 1; off < 64; off <<= 1) {
        int u = __shfl_up(v, off);
        if (tid >= off) v += u;
    }
    if (tid < nb) bsum[tid] = v - orig;
}

// phase 3: add block offsets, seed cursor, set edge_ptr[N]=E
__global__ __launch_bounds__(256) void scan3_kernel(
    int* __restrict__ edge_ptr, int* __restrict__ cursor,
    const int* __restrict__ bsum, int N, int E)
{
    const int g0 = (int)blockIdx.x * 1024 + (int)threadIdx.x * 4;
    const int b = bsum[blockIdx.x];
    #pragma unroll
    for (int i = 0; i < 4; ++i) {
        int g = g0 + i;
        if (g < N) { int v = edge_ptr[g] + b; edge_ptr[g] = v; cursor[g] = v; }
    }
    if (blockIdx.x == 0 && threadIdx.x == 0) edge_ptr[N] = E;
}

__global__ __launch_bounds__(256) void scatter_kernel(
    const int* __restrict__ rows, const int* __restrict__ cols,
    int* __restrict__ cursor, int* __restrict__ cols_sorted, int E)
{
    int e = (int)blockIdx.x * 256 + (int)threadIdx.x;
    if (e < E) {
        int pos = atomicAdd(&cursor[rows[e]], 1);
        cols_sorted[pos] = cols[e];
    }
}

// ---------------- aggregate: one wave per node, bf16 h, zero atomics ----------------
__global__ __launch_bounds__(256) void aggregate_kernel(
    const int* __restrict__ edge_ptr, const int* __restrict__ cols_sorted,
    const unsigned int* __restrict__ h2, float* __restrict__ out, int N)
{
    const int node = (int)blockIdx.x * 4 + ((int)threadIdx.x >> 6);
    if (node >= N) return;
    const int lane = threadIdx.x & 63;
    const int beg = edge_ptr[node], end = edge_ptr[node + 1];
    float2 acc = make_float2(0.0f, 0.0f);   // 0-init = empty-segment fill + clamp
    int i = beg;
    for (; i + 3 < end; i += 4) {           // 4-deep for memory-level parallelism
        unsigned int v0 = h2[(size_t)cols_sorted[i]     * 64 + lane];
        unsigned int v1 = h2[(size_t)cols_sorted[i + 1] * 64 + lane];
        unsigned int v2 = h2[(size_t)cols_sorted[i + 2] * 64 + lane];
        unsigned int v3 = h2[(size_t)cols_sorted[i + 3] * 64 + lane];
        acc.x = fmaxf(acc.x, fmaxf(fmaxf(__uint_as_float(v0 << 16), __uint_as_float(v1 << 16)),
                                   fmaxf(__uint_as_float(v2 << 16), __uint_as_float(v3 << 16))));
        acc.y = fmaxf(acc.y, fmaxf(fmaxf(__uint_as_float(v0 & 0xFFFF0000u), __uint_as_float(v1 & 0xFFFF0000u)),
                                   fmaxf(__uint_as_float(v2 & 0xFFFF0000u), __uint_as_float(v3 & 0xFFFF0000u))));
    }
    for (; i < end; ++i) {
        unsigned int v = h2[(size_t)cols_sorted[i] * 64 + lane];
        acc.x = fmaxf(acc.x, __uint_as_float(v << 16));
        acc.y = fmaxf(acc.y, __uint_as_float(v & 0xFFFF0000u));
    }
    ((float2*)out)[(size_t)node * 64 + lane] = acc;
}

extern "C" void kernel_launch(void* const* d_in, const int* in_sizes, int n_in,
                              void* d_out, int out_size, void* d_ws, size_t ws_size,
                              hipStream_t stream) {
    const float* x    = (const float*)d_in[0];
    const int*   ei   = (const int*)d_in[1];
    const float* W    = (const float*)d_in[2];
    const float* bias = (const float*)d_in[3];

    const int N = in_sizes[0] / D;   // 40000
    const int E = in_sizes[1] / 2;   // 640000
    const int* rows = ei;
    const int* cols = ei + E;

    // workspace layout (~13.3 MB)
    char* ws = (char*)d_ws;
    size_t off_h    = 0;                                        // N*D ushort
    size_t off_deg  = off_h   + (size_t)N * D * sizeof(unsigned short);
    size_t off_cur  = off_deg + (size_t)N * sizeof(int);
    size_t off_ptr  = off_cur + (size_t)N * sizeof(int);
    size_t off_bs   = off_ptr + (((size_t)(N + 1) * sizeof(int) + 15) & ~(size_t)15);
    size_t off_cs   = off_bs  + 64 * sizeof(int);

    unsigned short* h  = (unsigned short*)(ws + off_h);
    int* deg           = (int*)(ws + off_deg);
    int* cursor        = (int*)(ws + off_cur);
    int* edge_ptr      = (int*)(ws + off_ptr);
    int* bsum          = (int*)(ws + off_bs);
    int* cols_sorted   = (int*)(ws + off_cs);

    gemm_mfma_kernel<<<(N + 63) / 64, 256, 0, stream>>>(x, W, bias, h, N);

    hipMemsetAsync(deg, 0, (size_t)N * sizeof(int), stream);
    hist_kernel<<<(E + 255) / 256, 256, 0, stream>>>(rows, deg, E);

    const int nb = (N + 1023) / 1024;   // 40 (<= 64 for one-wave scan2)
    scan1_kernel<<<nb, 256, 0, stream>>>(deg, edge_ptr, bsum, N);
    scan2_kernel<<<1, 64, 0, stream>>>(bsum, nb);
    scan3_kernel<<<nb, 256, 0, stream>>>(edge_ptr, cursor, bsum, N, E);

    scatter_kernel<<<(E + 255) / 256, 256, 0, stream>>>(rows, cols, cursor,
                                                        cols_sorted, E);
    aggregate_kernel<<<(N + 3) / 4, 256, 0, stream>>>(edge_ptr, cols_sorted,
                                                      (const unsigned int*)h,
                                                      (float*)d_out, N);
}

// Round 4
// 179.117 us; speedup vs baseline: 5.1982x; 1.1100x over previous
//
#include <hip/hip_runtime.h>

#define D 128
#define PADK 136   // LDS row stride (elems): rows shift 4 banks, 2-way max (free)

typedef __attribute__((ext_vector_type(8))) short short8;
typedef __attribute__((ext_vector_type(4))) float floatx4;

// fp32 -> bf16 (RNE) raw bits
static __device__ __forceinline__ unsigned short f2b(float f) {
    union { float f; unsigned int u; } v; v.f = f;
    return (unsigned short)((v.u + 0x7FFFu + ((v.u >> 16) & 1u)) >> 16);
}

// ---------------- fused: GEMM(+bias+relu, MFMA bf16) | edge histogram ----------------
// blocks [0, GB): gemm on 64-row tiles.  blocks [GB, GB+HB): hist over edges.
__global__ __launch_bounds__(256) void gemm_hist_kernel(
    const float* __restrict__ x, const float* __restrict__ W,
    const float* __restrict__ bias, unsigned short* __restrict__ h, int M,
    const int* __restrict__ rows, int* __restrict__ deg, int E, int GB)
{
    if ((int)blockIdx.x >= GB) {
        // ---- histogram part ----
        int e = ((int)blockIdx.x - GB) * 256 + (int)threadIdx.x;
        if (e < E) atomicAdd(&deg[rows[e]], 1);
        return;
    }

    // ---- gemm part ----
    __shared__ unsigned short Wt[D * PADK];   // 34816 B
    __shared__ unsigned short Xs[64 * PADK];  // 17408 B

    const int tid = threadIdx.x;

    // stage W (fp32 [k][n]) -> Wt bf16 [n][k]
    for (int idx = tid * 4; idx < D * D; idx += 1024) {
        float4 w4 = *(const float4*)(W + idx);
        int k = idx >> 7, n = idx & (D - 1);
        Wt[(n + 0) * PADK + k] = f2b(w4.x);
        Wt[(n + 1) * PADK + k] = f2b(w4.y);
        Wt[(n + 2) * PADK + k] = f2b(w4.z);
        Wt[(n + 3) * PADK + k] = f2b(w4.w);
    }
    const int r0 = (int)blockIdx.x * 64;
    for (int idx = tid * 4; idx < 64 * D; idx += 1024) {
        int r = idx >> 7, k = idx & (D - 1);
        if (r0 + r < M) {
            float4 x4 = *(const float4*)(x + (size_t)(r0 + r) * D + k);
            Xs[r * PADK + k + 0] = f2b(x4.x);
            Xs[r * PADK + k + 1] = f2b(x4.y);
            Xs[r * PADK + k + 2] = f2b(x4.z);
            Xs[r * PADK + k + 3] = f2b(x4.w);
        }
    }
    __syncthreads();

    const int wave = tid >> 6, lane = tid & 63;
    const int rw = wave * 16;
    const int mrow = lane & 15, quad = lane >> 4;

    // A frag: lane holds A[m=lane&15][k = kc*32 + quad*8 + j]  (m89-verified)
    short8 a[4];
    #pragma unroll
    for (int kc = 0; kc < 4; ++kc)
        a[kc] = *(const short8*)(&Xs[(rw + mrow) * PADK + kc * 32 + quad * 8]);

    #pragma unroll
    for (int t = 0; t < 8; ++t) {
        const int n0 = t * 16;
        floatx4 acc = {0.f, 0.f, 0.f, 0.f};
        #pragma unroll
        for (int kc = 0; kc < 4; ++kc) {
            short8 b = *(const short8*)(&Wt[(n0 + mrow) * PADK + kc * 32 + quad * 8]);
            acc = __builtin_amdgcn_mfma_f32_16x16x32_bf16(a[kc], b, acc, 0, 0, 0);
        }
        const int col = n0 + mrow;
        const float bv = bias[col];
        #pragma unroll
        for (int r = 0; r < 4; ++r) {      // C/D: col=lane&15, row=quad*4+reg
            int row = r0 + rw + quad * 4 + r;
            if (row < M)
                h[(size_t)row * D + col] = f2b(fmaxf(acc[r] + bv, 0.0f));
        }
    }
}

// phase 1: per-block (1024 elems) local exclusive scan + block sums
__global__ __launch_bounds__(256) void scan1_kernel(
    const int* __restrict__ deg, int* __restrict__ edge_ptr,
    int* __restrict__ bsum, int N)
{
    __shared__ int part[256];
    const int tid = threadIdx.x;
    const int g0 = (int)blockIdx.x * 1024 + tid * 4;
    int d0 = 0, d1 = 0, d2 = 0, d3 = 0;
    if (g0 + 3 < N) {
        int4 d = *(const int4*)(deg + g0);
        d0 = d.x; d1 = d.y; d2 = d.z; d3 = d.w;
    } else {
        if (g0 + 0 < N) d0 = deg[g0 + 0];
        if (g0 + 1 < N) d1 = deg[g0 + 1];
        if (g0 + 2 < N) d2 = deg[g0 + 2];
        if (g0 + 3 < N) d3 = deg[g0 + 3];
    }
    const int s = d0 + d1 + d2 + d3;
    part[tid] = s;
    __syncthreads();
    for (int off = 1; off < 256; off <<= 1) {
        int v = (tid >= off) ? part[tid - off] : 0;
        __syncthreads();
        part[tid] += v;
        __syncthreads();
    }
    int ex = part[tid] - s;
    if (tid == 255) bsum[blockIdx.x] = part[255];
    if (g0 + 0 < N) edge_ptr[g0 + 0] = ex; ex += d0;
    if (g0 + 1 < N) edge_ptr[g0 + 1] = ex; ex += d1;
    if (g0 + 2 < N) edge_ptr[g0 + 2] = ex; ex += d2;
    if (g0 + 3 < N) edge_ptr[g0 + 3] = ex;
}

// fused phase 2+3: every block redundantly wave-scans the <=64 block sums,
// then adds its own offset, seeds cursor, sets edge_ptr[N]=E.
__global__ __launch_bounds__(256) void scan23_kernel(
    int* __restrict__ edge_ptr, int* __restrict__ cursor,
    const int* __restrict__ bsum, int N, int E, int nb)
{
    __shared__ int soff[64];
    const int tid = threadIdx.x;
    if (tid < 64) {
        int v = (tid < nb) ? bsum[tid] : 0;
        const int orig = v;
        for (int off = 1; off < 64; off <<= 1) {
            int u = __shfl_up(v, off);
            if (tid >= off) v += u;
        }
        soff[tid] = v - orig;   // exclusive
    }
    __syncthreads();
    const int b = soff[blockIdx.x];
    const int g0 = (int)blockIdx.x * 1024 + tid * 4;
    #pragma unroll
    for (int i = 0; i < 4; ++i) {
        int g = g0 + i;
        if (g < N) { int v = edge_ptr[g] + b; edge_ptr[g] = v; cursor[g] = v; }
    }
    if (blockIdx.x == 0 && tid == 0) edge_ptr[N] = E;
}

__global__ __launch_bounds__(256) void scatter_kernel(
    const int* __restrict__ rows, const int* __restrict__ cols,
    int* __restrict__ cursor, int* __restrict__ cols_sorted, int E)
{
    int e = (int)blockIdx.x * 256 + (int)threadIdx.x;
    if (e < E) {
        int pos = atomicAdd(&cursor[rows[e]], 1);
        cols_sorted[pos] = cols[e];
    }
}

// aggregate: one wave per node, bf16 h, zero atomics.
__global__ __launch_bounds__(256) void aggregate_kernel(
    const int* __restrict__ edge_ptr, const int* __restrict__ cols_sorted,
    const unsigned int* __restrict__ h2, float* __restrict__ out, int N)
{
    const int node = (int)blockIdx.x * 4 + ((int)threadIdx.x >> 6);
    if (node >= N) return;
    const int lane = threadIdx.x & 63;
    const int beg = edge_ptr[node], end = edge_ptr[node + 1];
    float2 acc = make_float2(0.0f, 0.0f);   // 0-init = empty-segment fill + clamp
    int i = beg;
    for (; i + 3 < end; i += 4) {           // 4-deep MLP
        unsigned int v0 = h2[(size_t)cols_sorted[i]     * 64 + lane];
        unsigned int v1 = h2[(size_t)cols_sorted[i + 1] * 64 + lane];
        unsigned int v2 = h2[(size_t)cols_sorted[i + 2] * 64 + lane];
        unsigned int v3 = h2[(size_t)cols_sorted[i + 3] * 64 + lane];
        acc.x = fmaxf(acc.x, fmaxf(fmaxf(__uint_as_float(v0 << 16), __uint_as_float(v1 << 16)),
                                   fmaxf(__uint_as_float(v2 << 16), __uint_as_float(v3 << 16))));
        acc.y = fmaxf(acc.y, fmaxf(fmaxf(__uint_as_float(v0 & 0xFFFF0000u), __uint_as_float(v1 & 0xFFFF0000u)),
                                   fmaxf(__uint_as_float(v2 & 0xFFFF0000u), __uint_as_float(v3 & 0xFFFF0000u))));
    }
    for (; i < end; ++i) {
        unsigned int v = h2[(size_t)cols_sorted[i] * 64 + lane];
        acc.x = fmaxf(acc.x, __uint_as_float(v << 16));
        acc.y = fmaxf(acc.y, __uint_as_float(v & 0xFFFF0000u));
    }
    ((float2*)out)[(size_t)node * 64 + lane] = acc;
}

extern "C" void kernel_launch(void* const* d_in, const int* in_sizes, int n_in,
                              void* d_out, int out_size, void* d_ws, size_t ws_size,
                              hipStream_t stream) {
    const float* x    = (const float*)d_in[0];
    const int*   ei   = (const int*)d_in[1];
    const float* W    = (const float*)d_in[2];
    const float* bias = (const float*)d_in[3];

    const int N = in_sizes[0] / D;   // 40000
    const int E = in_sizes[1] / 2;   // 640000
    const int* rows = ei;
    const int* cols = ei + E;

    // workspace layout (~13.3 MB)
    char* ws = (char*)d_ws;
    size_t off_h    = 0;                                        // N*D ushort
    size_t off_deg  = off_h   + (size_t)N * D * sizeof(unsigned short);
    size_t off_cur  = off_deg + (size_t)N * sizeof(int);
    size_t off_ptr  = off_cur + (size_t)N * sizeof(int);
    size_t off_bs   = off_ptr + (((size_t)(N + 1) * sizeof(int) + 15) & ~(size_t)15);
    size_t off_cs   = off_bs  + 64 * sizeof(int);

    unsigned short* h  = (unsigned short*)(ws + off_h);
    int* deg           = (int*)(ws + off_deg);
    int* cursor        = (int*)(ws + off_cur);
    int* edge_ptr      = (int*)(ws + off_ptr);
    int* bsum          = (int*)(ws + off_bs);
    int* cols_sorted   = (int*)(ws + off_cs);

    hipMemsetAsync(deg, 0, (size_t)N * sizeof(int), stream);

    const int GB = (N + 63) / 64;        // 625 gemm blocks
    const int HB = (E + 255) / 256;      // 2500 hist blocks
    gemm_hist_kernel<<<GB + HB, 256, 0, stream>>>(x, W, bias, h, N,
                                                  rows, deg, E, GB);

    const int nb = (N + 1023) / 1024;    // 40 (<= 64 for one-wave scan)
    scan1_kernel<<<nb, 256, 0, stream>>>(deg, edge_ptr, bsum, N);
    scan23_kernel<<<nb, 256, 0, stream>>>(edge_ptr, cursor, bsum, N, E, nb);

    scatter_kernel<<<HB, 256, 0, stream>>>(rows, cols, cursor, cols_sorted, E);
    aggregate_kernel<<<(N + 3) / 4, 256, 0, stream>>>(edge_ptr, cols_sorted,
                                                      (const unsigned int*)h,
                                                      (float*)d_out, N);
}